// Round 5
// baseline (668.747 us; speedup 1.0000x reference)
//
#include <hip/hip_runtime.h>

#define K_DIM 512
#define S_DIM 64
#define T_LEN 64
#define BW    16      // sequences per workgroup
#define NWG   32      // 32 workgroups x 16 seqs = 512
#define XPAD  8       // Xb row padding (elements)

typedef float f32x4 __attribute__((ext_vector_type(4)));
typedef short bf16x8 __attribute__((ext_vector_type(8)));

__device__ __forceinline__ short f2bf(float f) {
    unsigned u = __builtin_bit_cast(unsigned, f);
    u += 0x7fffu + ((u >> 16) & 1u);   // round-to-nearest-even
    return (short)(u >> 16);
}

// ---------------- pre-pass: build bf16/derived operands in workspace ----------------
__global__ void ssm_prep(const float* __restrict__ A, const float* __restrict__ B,
                         const float* __restrict__ C, const float* __restrict__ Pp,
                         short* __restrict__ A16, short* __restrict__ Ceff16,
                         float* __restrict__ PI32, float* __restrict__ PB32) {
    int i = blockIdx.x * blockDim.x + threadIdx.x;
    int stride = gridDim.x * blockDim.x;
    for (int idx = i; idx < K_DIM * K_DIM; idx += stride)
        A16[idx] = f2bf(A[idx]);
    for (int idx = i; idx < S_DIM * K_DIM; idx += stride) {
        int s = idx >> 9;               // K_DIM == 512
        int k = idx & (K_DIM - 1);
        float p = 1.0f / (1.0f + expf(-Pp[idx]));
        PI32[idx]   = p;
        Ceff16[idx] = f2bf(C[idx] * p);
        PB32[idx]   = p * B[k * S_DIM + s];   // pi[s][k] * B[k][s]
    }
}

#define MFMA_(xa, fb, acc) acc = __builtin_amdgcn_mfma_f32_16x16x32_bf16(xa, fb, acc, 0, 0, 0)

// load group g: fragments for k-slices 2g and 2g+1, both nt halves.
// All names are distinct SSA temporaries -- no arrays, nothing to scratch.
#define LOADG(g) \
    bf16x8 fa0_##g = *(const bf16x8*)(aP0 + (((2*(g)  ) & 15) * 32)); \
    bf16x8 fb0_##g = *(const bf16x8*)(aP1 + (((2*(g)  ) & 15) * 32)); \
    bf16x8 fa1_##g = *(const bf16x8*)(aP0 + (((2*(g)+1) & 15) * 32)); \
    bf16x8 fb1_##g = *(const bf16x8*)(aP1 + (((2*(g)+1) & 15) * 32));

#define COMPG(g) { \
    bf16x8 xa0 = *(const bf16x8*)(&Xb[lr][(2*(g)) * 32 + 8 * lg]); \
    MFMA_(xa0, fa0_##g, acc0); \
    MFMA_(xa0, fb0_##g, acc1); \
    bf16x8 xa1 = *(const bf16x8*)(&Xb[lr][(2*(g)+1) * 32 + 8 * lg]); \
    MFMA_(xa1, fa1_##g, acc0); \
    MFMA_(xa1, fb1_##g, acc1); }

// ---------------- main: 32 WGs x 1024 threads (16 waves), 16 seqs/WG, 64 steps ----------------
__global__ __launch_bounds__(1024) __attribute__((amdgpu_waves_per_eu(4, 4)))
void ssm_main(
    const short* __restrict__ A16,     // [K][K] bf16 row-major
    const short* __restrict__ Ceff16,  // [S][K] bf16
    const float* __restrict__ PI32,    // [S][K]
    const float* __restrict__ PB32,    // [S][K]
    const float* __restrict__ init,    // [K]
    const int*   __restrict__ tokens,  // [BSZ][T]
    float*       __restrict__ out)     // [BSZ]
{
    __shared__ short Xb[BW][K_DIM + XPAD];      // bf16 state (MFMA A-operand)
    __shared__ float Lg[4][BW][S_DIM + 5];      // logits partials (4 K-quarters)
    __shared__ int   tokS[BW][T_LEN];

    const int tid = threadIdx.x;
    const int w  = tid >> 6;     // wave 0..15, owns k-range [w*32, w*32+32)
    const int l  = tid & 63;
    const int lg = l >> 4;       // lane group 0..3
    const int lr = l & 15;       // row/col index within MFMA tile
    const int b0 = blockIdx.x * BW;

    for (int idx = tid; idx < BW * T_LEN; idx += 1024) {
        int r = idx >> 6, t = idx & 63;
        tokS[r][t] = tokens[(b0 + r) * T_LEN + t];
    }
    for (int idx = tid; idx < BW * K_DIM; idx += 1024) {
        int r = idx >> 9, k = idx & (K_DIM - 1);
        Xb[r][k] = f2bf(init[k]);
    }
    // fp32 master state: xm[nt][e] = x[b=4*lg+e][k=w*32+nt*16+lr]
    float xm[2][4];
    #pragma unroll
    for (int nt = 0; nt < 2; ++nt) {
        float iv = init[w * 32 + nt * 16 + lr];
        #pragma unroll
        for (int e = 0; e < 4; ++e) xm[nt][e] = iv;
    }

    const int sq = w & 3;    // logits s-tile
    const int qh = w >> 2;   // logits K-quarter

    // A-fragment bases: nt=0 rows (k = w*32+lr), nt=1 rows (k = w*32+16+lr)
    const short* aP0 = A16 + (w * 32 +      lr) * K_DIM + 8 * lg;
    const short* aP1 = A16 + (w * 32 + 16 + lr) * K_DIM + 8 * lg;
    const short* cP  = Ceff16 + (sq * 16 + lr) * K_DIM + qh * 128 + 8 * lg;

    float llacc = 0.0f;
    __syncthreads();

    for (int t = 0; t < T_LEN; ++t) {
        // ---- P1: logits partial GEMM (K-quarter qh): 4 cb loads + 4 MFMA
        f32x4 lga = {0.f, 0.f, 0.f, 0.f};
        {
            bf16x8 cb0 = *(const bf16x8*)(cP);
            bf16x8 cb1 = *(const bf16x8*)(cP + 32);
            bf16x8 cb2 = *(const bf16x8*)(cP + 64);
            bf16x8 cb3 = *(const bf16x8*)(cP + 96);
            bf16x8 x0 = *(const bf16x8*)(&Xb[lr][qh * 128 +  0 + 8 * lg]);
            MFMA_(x0, cb0, lga);
            bf16x8 x1 = *(const bf16x8*)(&Xb[lr][qh * 128 + 32 + 8 * lg]);
            MFMA_(x1, cb1, lga);
            bf16x8 x2 = *(const bf16x8*)(&Xb[lr][qh * 128 + 64 + 8 * lg]);
            MFMA_(x2, cb2, lga);
            bf16x8 x3 = *(const bf16x8*)(&Xb[lr][qh * 128 + 96 + 8 * lg]);
            MFMA_(x3, cb3, lga);
        }
        #pragma unroll
        for (int e = 0; e < 4; ++e)
            Lg[qh][4 * lg + e][sq * 16 + lr] = lga[e];

        // ---- issue gating gathers here (~600 cy of P2 cover before P3 consumes)
        int mytok[4];
        #pragma unroll
        for (int e = 0; e < 4; ++e) mytok[e] = tokS[4 * lg + e][t];
        float pi_v[2][4], pb_v[2][4];
        #pragma unroll
        for (int nt = 0; nt < 2; ++nt) {
            int k = w * 32 + nt * 16 + lr;
            #pragma unroll
            for (int e = 0; e < 4; ++e) {
                pi_v[nt][e] = PI32[mytok[e] * K_DIM + k];
                pb_v[nt][e] = PB32[mytok[e] * K_DIM + k];
            }
        }

        // ---- P2: update GEMM, explicit depth-3 group pipeline (all SSA temps)
        f32x4 acc0 = {0.f, 0.f, 0.f, 0.f};
        f32x4 acc1 = {0.f, 0.f, 0.f, 0.f};
        LOADG(0)
        LOADG(1)
        LOADG(2)
        COMPG(0) LOADG(3)
        COMPG(1) LOADG(4)
        COMPG(2) LOADG(5)
        COMPG(3) LOADG(6)
        COMPG(4) LOADG(7)
        COMPG(5)
        COMPG(6)
        COMPG(7)
        __syncthreads();   // Xb reads done; Lg writes visible

        // ---- P3: gating in fp32, rewrite Xb
        #pragma unroll
        for (int nt = 0; nt < 2; ++nt) {
            int k = w * 32 + nt * 16 + lr;
            #pragma unroll
            for (int e = 0; e < 4; ++e) {
                float a  = (nt == 0) ? acc0[e] : acc1[e];
                float p  = pi_v[nt][e];
                float nx = xm[nt][e] + p * (a - xm[nt][e]) + pb_v[nt][e];
                xm[nt][e] = nx;
                Xb[4 * lg + e][k] = f2bf(nx);
            }
        }
        // waves 0..3: log-softmax + LL for 4 seqs each (16 lanes/seq, 4 logits/lane)
        if (w < 4) {
            int b = w * 4 + (l >> 4);
            int i = l & 15;
            float v[4];
            #pragma unroll
            for (int c = 0; c < 4; ++c)
                v[c] = Lg[0][b][i * 4 + c] + Lg[1][b][i * 4 + c]
                     + Lg[2][b][i * 4 + c] + Lg[3][b][i * 4 + c];
            float m = fmaxf(fmaxf(v[0], v[1]), fmaxf(v[2], v[3]));
            m = fmaxf(m, __shfl_xor(m, 1));
            m = fmaxf(m, __shfl_xor(m, 2));
            m = fmaxf(m, __shfl_xor(m, 4));
            m = fmaxf(m, __shfl_xor(m, 8));
            float sum = expf(v[0] - m) + expf(v[1] - m) + expf(v[2] - m) + expf(v[3] - m);
            sum += __shfl_xor(sum, 1);
            sum += __shfl_xor(sum, 2);
            sum += __shfl_xor(sum, 4);
            sum += __shfl_xor(sum, 8);
            int tok = tokS[b][t];
            float sel = (i == (tok >> 2)) ? v[tok & 3] : 0.0f;
            sel += __shfl_xor(sel, 1);
            sel += __shfl_xor(sel, 2);
            sel += __shfl_xor(sel, 4);
            sel += __shfl_xor(sel, 8);
            llacc += sel - m - logf(sum);
        }
        __syncthreads();   // new Xb visible; Lg consumed
    }

    if (w < 4 && (l & 15) == 0)
        out[b0 + w * 4 + (l >> 4)] = llacc;
}

extern "C" void kernel_launch(void* const* d_in, const int* in_sizes, int n_in,
                              void* d_out, int out_size, void* d_ws, size_t ws_size,
                              hipStream_t stream) {
    const float* A  = (const float*)d_in[0];   // (512,512)
    const float* B  = (const float*)d_in[1];   // (512,64)
    const float* C  = (const float*)d_in[2];   // (64,512)
    const float* Pp = (const float*)d_in[3];   // (64,512)
    const float* init = (const float*)d_in[4]; // (512,)
    const int* tokens = (const int*)d_in[5];   // (512,64)
    float* out = (float*)d_out;

    // workspace layout (needs 851,968 bytes)
    short* A16    = (short*)d_ws;                              // 512*512*2 = 524288
    short* Ceff16 = (short*)((char*)d_ws + 524288);            // 64*512*2  =  65536
    float* PI32   = (float*)((char*)d_ws + 589824);            // 64*512*4  = 131072
    float* PB32   = (float*)((char*)d_ws + 720896);            // 64*512*4  = 131072

    ssm_prep<<<256, 256, 0, stream>>>(A, B, C, Pp, A16, Ceff16, PI32, PB32);
    ssm_main<<<NWG, 1024, 0, stream>>>(A16, Ceff16, PI32, PB32, init, tokens, out);
}

// Round 6
// 573.701 us; speedup vs baseline: 1.1657x; 1.1657x over previous
//
#include <hip/hip_runtime.h>

#define K_DIM 512
#define S_DIM 64
#define T_LEN 64
#define BW    16      // sequences per workgroup
#define NWG   32      // 32 workgroups x 16 seqs = 512
#define XPAD  8       // Xb row pad: stride 1040B -> 4-bank lane shift, 2-way (free)
#define CPAD  8       // Cb row pad: same

typedef float f32x4 __attribute__((ext_vector_type(4)));
typedef short bf16x8 __attribute__((ext_vector_type(8)));

__device__ __forceinline__ short f2bf(float f) {
    unsigned u = __builtin_bit_cast(unsigned, f);
    u += 0x7fffu + ((u >> 16) & 1u);   // round-to-nearest-even
    return (short)(u >> 16);
}

// ---------------- pre-pass: build bf16/derived operands in workspace ----------------
__global__ void ssm_prep(const float* __restrict__ A, const float* __restrict__ B,
                         const float* __restrict__ C, const float* __restrict__ Pp,
                         short* __restrict__ A16, short* __restrict__ Ceff16,
                         float* __restrict__ PI32, float* __restrict__ PB32) {
    int i = blockIdx.x * blockDim.x + threadIdx.x;
    int stride = gridDim.x * blockDim.x;
    for (int idx = i; idx < K_DIM * K_DIM; idx += stride)
        A16[idx] = f2bf(A[idx]);
    for (int idx = i; idx < S_DIM * K_DIM; idx += stride) {
        int s = idx >> 9;               // K_DIM == 512
        int k = idx & (K_DIM - 1);
        float p = 1.0f / (1.0f + expf(-Pp[idx]));
        PI32[idx]   = p;
        Ceff16[idx] = f2bf(C[idx] * p);
        PB32[idx]   = p * B[k * S_DIM + s];   // pi[s][k] * B[k][s]
    }
}

#define MFMA_(xa, fb, acc) acc = __builtin_amdgcn_mfma_f32_16x16x32_bf16(xa, fb, acc, 0, 0, 0)

// one k-slice (32 wide): A-fragments for both nt halves. Distinct SSA names.
#define LOADS(s) \
    bf16x8 fa_##s = *(const bf16x8*)(aP0 + (s) * 32); \
    bf16x8 fb_##s = *(const bf16x8*)(aP1 + (s) * 32);

#define COMPS(s) { \
    bf16x8 xa = *(const bf16x8*)(&Xb[lr][(s) * 32 + 8 * lg]); \
    MFMA_(xa, fa_##s, acc0); \
    MFMA_(xa, fb_##s, acc1); }

// ---------------- main: 32 WGs x 1024 threads (16 waves), 16 seqs/WG, 64 steps ----------------
// LDS deliberately >53KB so only 1 WG/CU fits -> backend derives 4 waves/EU ->
// 128-VGPR budget (R3-R5: 37.5KB LDS -> derived 8 waves/EU -> 64 VGPR + scratch
// spill, WRITE_SIZE 9-10MB). With only 32 WGs on 256 CUs, >1 WG/CU never
// happened anyway; the extra LDS productively caches Ceff.
__global__ __launch_bounds__(1024) __attribute__((amdgpu_waves_per_eu(4, 4)))
void ssm_main(
    const short* __restrict__ A16,     // [K][K] bf16 row-major
    const short* __restrict__ Ceff16,  // [S][K] bf16
    const float* __restrict__ PI32,    // [S][K]
    const float* __restrict__ PB32,    // [S][K]
    const float* __restrict__ init,    // [K]
    const int*   __restrict__ tokens,  // [BSZ][T]
    float*       __restrict__ out)     // [BSZ]
{
    __shared__ short Xb[BW][K_DIM + XPAD];       // 16.6 KB  bf16 state
    __shared__ short Cb[S_DIM][K_DIM + CPAD];    // 66.6 KB  Ceff tile (step-invariant)
    __shared__ float Lg[4][BW][S_DIM + 5];       // 17.7 KB  logits partials
    __shared__ int   tokS[BW][T_LEN];            //  4.1 KB

    const int tid = threadIdx.x;
    const int w  = tid >> 6;     // wave 0..15, owns k-range [w*32, w*32+32)
    const int l  = tid & 63;
    const int lg = l >> 4;       // lane group 0..3
    const int lr = l & 15;       // row/col index within MFMA tile
    const int b0 = blockIdx.x * BW;

    for (int idx = tid; idx < BW * T_LEN; idx += 1024) {
        int r = idx >> 6, t = idx & 63;
        tokS[r][t] = tokens[(b0 + r) * T_LEN + t];
    }
    for (int idx = tid; idx < BW * K_DIM; idx += 1024) {
        int r = idx >> 9, k = idx & (K_DIM - 1);
        Xb[r][k] = f2bf(init[k]);
    }
    // stage Ceff into LDS once (4 iters x 1024 threads x 16B)
    for (int idx = tid; idx < (S_DIM * K_DIM) / 8; idx += 1024) {
        int r = idx >> 6, c8 = (idx & 63) * 8;
        *(bf16x8*)&Cb[r][c8] = *(const bf16x8*)(Ceff16 + r * K_DIM + c8);
    }
    // fp32 master state: xm[nt][e] = x[b=4*lg+e][k=w*32+nt*16+lr]
    float xm[2][4];
    #pragma unroll
    for (int nt = 0; nt < 2; ++nt) {
        float iv = init[w * 32 + nt * 16 + lr];
        #pragma unroll
        for (int e = 0; e < 4; ++e) xm[nt][e] = iv;
    }

    const int sq = w & 3;    // logits s-tile
    const int qh = w >> 2;   // logits K-quarter

    // A-fragment bases: nt=0 rows (k = w*32+lr), nt=1 rows (k = w*32+16+lr)
    const short* aP0 = A16 + (w * 32 +      lr) * K_DIM + 8 * lg;
    const short* aP1 = A16 + (w * 32 + 16 + lr) * K_DIM + 8 * lg;

    float llacc = 0.0f;
    __syncthreads();

    for (int t = 0; t < T_LEN; ++t) {
        // ---- P1: logits partial GEMM (K-quarter qh), all-LDS operands
        f32x4 lga = {0.f, 0.f, 0.f, 0.f};
        #pragma unroll
        for (int i = 0; i < 4; ++i) {
            bf16x8 xa = *(const bf16x8*)(&Xb[lr][qh * 128 + i * 32 + 8 * lg]);
            bf16x8 cb = *(const bf16x8*)(&Cb[sq * 16 + lr][qh * 128 + i * 32 + 8 * lg]);
            MFMA_(xa, cb, lga);
        }
        #pragma unroll
        for (int e = 0; e < 4; ++e)
            Lg[qh][4 * lg + e][sq * 16 + lr] = lga[e];

        // ---- issue gating gathers (consumed in P3; covered by P2)
        int mytok[4];
        #pragma unroll
        for (int e = 0; e < 4; ++e) mytok[e] = tokS[4 * lg + e][t];
        float pi_v[2][4], pb_v[2][4];
        #pragma unroll
        for (int nt = 0; nt < 2; ++nt) {
            int k = w * 32 + nt * 16 + lr;
            #pragma unroll
            for (int e = 0; e < 4; ++e) {
                pi_v[nt][e] = PI32[mytok[e] * K_DIM + k];
                pb_v[nt][e] = PB32[mytok[e] * K_DIM + k];
            }
        }

        // ---- P2: update GEMM, in-step depth-8 slice pipeline (SSA temps only)
        f32x4 acc0 = {0.f, 0.f, 0.f, 0.f};
        f32x4 acc1 = {0.f, 0.f, 0.f, 0.f};
        LOADS(0) LOADS(1) LOADS(2) LOADS(3)
        LOADS(4) LOADS(5) LOADS(6) LOADS(7)
        COMPS(0)  LOADS(8)
        COMPS(1)  LOADS(9)
        COMPS(2)  LOADS(10)
        COMPS(3)  LOADS(11)
        COMPS(4)  LOADS(12)
        COMPS(5)  LOADS(13)
        COMPS(6)  LOADS(14)
        COMPS(7)  LOADS(15)
        COMPS(8)  COMPS(9)  COMPS(10) COMPS(11)
        COMPS(12) COMPS(13) COMPS(14) COMPS(15)
        __syncthreads();   // Xb reads done; Lg writes visible

        // ---- P3: gating in fp32, rewrite Xb
        #pragma unroll
        for (int nt = 0; nt < 2; ++nt) {
            int k = w * 32 + nt * 16 + lr;
            #pragma unroll
            for (int e = 0; e < 4; ++e) {
                float a  = (nt == 0) ? acc0[e] : acc1[e];
                float p  = pi_v[nt][e];
                float nx = xm[nt][e] + p * (a - xm[nt][e]) + pb_v[nt][e];
                xm[nt][e] = nx;
                Xb[4 * lg + e][k] = f2bf(nx);
            }
        }
        // waves 0..3: log-softmax + LL for 4 seqs each (16 lanes/seq, 4 logits/lane)
        if (w < 4) {
            int b = w * 4 + (l >> 4);
            int i = l & 15;
            float v[4];
            #pragma unroll
            for (int c = 0; c < 4; ++c)
                v[c] = Lg[0][b][i * 4 + c] + Lg[1][b][i * 4 + c]
                     + Lg[2][b][i * 4 + c] + Lg[3][b][i * 4 + c];
            float m = fmaxf(fmaxf(v[0], v[1]), fmaxf(v[2], v[3]));
            m = fmaxf(m, __shfl_xor(m, 1));
            m = fmaxf(m, __shfl_xor(m, 2));
            m = fmaxf(m, __shfl_xor(m, 4));
            m = fmaxf(m, __shfl_xor(m, 8));
            float sum = expf(v[0] - m) + expf(v[1] - m) + expf(v[2] - m) + expf(v[3] - m);
            sum += __shfl_xor(sum, 1);
            sum += __shfl_xor(sum, 2);
            sum += __shfl_xor(sum, 4);
            sum += __shfl_xor(sum, 8);
            int tok = tokS[b][t];
            float sel = (i == (tok >> 2)) ? v[tok & 3] : 0.0f;
            sel += __shfl_xor(sel, 1);
            sel += __shfl_xor(sel, 2);
            sel += __shfl_xor(sel, 4);
            sel += __shfl_xor(sel, 8);
            llacc += sel - m - logf(sum);
        }
        __syncthreads();   // new Xb visible; Lg consumed
    }

    if (w < 4 && (l & 15) == 0)
        out[b0 + w * 4 + (l >> 4)] = llacc;
}

extern "C" void kernel_launch(void* const* d_in, const int* in_sizes, int n_in,
                              void* d_out, int out_size, void* d_ws, size_t ws_size,
                              hipStream_t stream) {
    const float* A  = (const float*)d_in[0];   // (512,512)
    const float* B  = (const float*)d_in[1];   // (512,64)
    const float* C  = (const float*)d_in[2];   // (64,512)
    const float* Pp = (const float*)d_in[3];   // (64,512)
    const float* init = (const float*)d_in[4]; // (512,)
    const int* tokens = (const int*)d_in[5];   // (512,64)
    float* out = (float*)d_out;

    // workspace layout (needs 851,968 bytes)
    short* A16    = (short*)d_ws;                              // 512*512*2 = 524288
    short* Ceff16 = (short*)((char*)d_ws + 524288);            // 64*512*2  =  65536
    float* PI32   = (float*)((char*)d_ws + 589824);            // 64*512*4  = 131072
    float* PB32   = (float*)((char*)d_ws + 720896);            // 64*512*4  = 131072

    ssm_prep<<<256, 256, 0, stream>>>(A, B, C, Pp, A16, Ceff16, PI32, PB32);
    ssm_main<<<NWG, 1024, 0, stream>>>(A16, Ceff16, PI32, PB32, init, tokens, out);
}

// Round 7
// 452.709 us; speedup vs baseline: 1.4772x; 1.2673x over previous
//
#include <hip/hip_runtime.h>

#define K_DIM 512
#define S_DIM 64
#define T_LEN 64
#define BW    16      // sequences per workgroup
#define NWG   32      // 32 workgroups x 16 seqs = 512
#define XPAD  8       // Xb row pad: stride 1040B -> 2-way bank aliasing only (free)
#define CPAD  8       // Cb row pad: same

typedef float f32x4 __attribute__((ext_vector_type(4)));
typedef short bf16x8 __attribute__((ext_vector_type(8)));

__device__ __forceinline__ short f2bf(float f) {
    unsigned u = __builtin_bit_cast(unsigned, f);
    u += 0x7fffu + ((u >> 16) & 1u);   // round-to-nearest-even
    return (short)(u >> 16);
}

// ---------------- pre-pass: build bf16/derived operands in workspace ----------------
__global__ void ssm_prep(const float* __restrict__ A, const float* __restrict__ B,
                         const float* __restrict__ C, const float* __restrict__ Pp,
                         short* __restrict__ A16, short* __restrict__ Ceff16,
                         float* __restrict__ PI32, float* __restrict__ PB32) {
    int i = blockIdx.x * blockDim.x + threadIdx.x;
    int stride = gridDim.x * blockDim.x;
    for (int idx = i; idx < K_DIM * K_DIM; idx += stride)
        A16[idx] = f2bf(A[idx]);
    for (int idx = i; idx < S_DIM * K_DIM; idx += stride) {
        int s = idx >> 9;               // K_DIM == 512
        int k = idx & (K_DIM - 1);
        float p = 1.0f / (1.0f + expf(-Pp[idx]));
        PI32[idx]   = p;
        Ceff16[idx] = f2bf(C[idx] * p);
        PB32[idx]   = p * B[k * S_DIM + s];   // pi[s][k] * B[k][s]
    }
}

#define MFMA_(xa, fb, acc) acc = __builtin_amdgcn_mfma_f32_16x16x32_bf16(xa, fb, acc, 0, 0, 0)

// resident A-fragments (nt=0,1 halves): 32 named SSA vars = 128 VGPRs, loaded
// once before the t-loop, read-only for all 64 steps.
#define RESL(s) \
    bf16x8 ra_##s = *(const bf16x8*)(aP0 + (s) * 32); \
    bf16x8 rb_##s = *(const bf16x8*)(aP1 + (s) * 32);

// streamed A-fragments (nt=2,3 halves): in-step pipeline, SSA temps only
#define LOADS(s) \
    bf16x8 fc_##s = *(const bf16x8*)(aP2 + (s) * 32); \
    bf16x8 fd_##s = *(const bf16x8*)(aP3 + (s) * 32);

#define COMPS(s) { \
    bf16x8 xa = *(const bf16x8*)(&Xb[lr][(s) * 32 + 8 * lg]); \
    MFMA_(xa, ra_##s, acc0); \
    MFMA_(xa, rb_##s, acc1); \
    MFMA_(xa, fc_##s, acc2); \
    MFMA_(xa, fd_##s, acc3); }

// ---------------- main: 32 WGs x 512 threads (8 waves), 16 seqs/WG, 64 steps ----------------
// 512 threads + LDS 94KB -> 1 WG/CU -> 2 waves/EU -> 256-VGPR budget per wave.
// (R3-R6: 1024-thread waves were pinned at 64 VGPRs regardless of attributes;
// the register pipeline could not exist. Here half of each wave's A-slice is
// permanently register-resident, halving per-step L2 traffic outright.)
__global__ __launch_bounds__(512) __attribute__((amdgpu_waves_per_eu(2, 2)))
void ssm_main(
    const short* __restrict__ A16,     // [K][K] bf16 row-major
    const short* __restrict__ Ceff16,  // [S][K] bf16
    const float* __restrict__ PI32,    // [S][K]
    const float* __restrict__ PB32,    // [S][K]
    const float* __restrict__ init,    // [K]
    const int*   __restrict__ tokens,  // [BSZ][T]
    float*       __restrict__ out)     // [BSZ]
{
    __shared__ short Xb[BW][K_DIM + XPAD];       // 16.6 KB  bf16 state
    __shared__ short Cb[S_DIM][K_DIM + CPAD];    // 66.6 KB  Ceff tile (step-invariant)
    __shared__ float Lg[2][BW][S_DIM + 5];       //  8.8 KB  logits partials (2 K-halves)
    __shared__ int   tokS[BW][T_LEN];            //  4.1 KB   (total ~96 KB > 80 KB -> 1 WG/CU)

    const int tid = threadIdx.x;
    const int w  = tid >> 6;     // wave 0..7, owns k-range [w*64, w*64+64)
    const int l  = tid & 63;
    const int lg = l >> 4;       // lane group 0..3
    const int lr = l & 15;       // row/col index within MFMA tile
    const int b0 = blockIdx.x * BW;

    for (int idx = tid; idx < BW * T_LEN; idx += 512) {
        int r = idx >> 6, t = idx & 63;
        tokS[r][t] = tokens[(b0 + r) * T_LEN + t];
    }
    for (int idx = tid; idx < BW * K_DIM; idx += 512) {
        int r = idx >> 9, k = idx & (K_DIM - 1);
        Xb[r][k] = f2bf(init[k]);
    }
    // stage Ceff into LDS once
    for (int idx = tid; idx < (S_DIM * K_DIM) / 8; idx += 512) {
        int r = idx >> 6, c8 = (idx & 63) * 8;
        *(bf16x8*)&Cb[r][c8] = *(const bf16x8*)(Ceff16 + r * K_DIM + c8);
    }
    // fp32 master state: xm[nt][e] = x[b=4*lg+e][k=w*64+nt*16+lr]
    float xm[4][4];
    #pragma unroll
    for (int nt = 0; nt < 4; ++nt) {
        float iv = init[w * 64 + nt * 16 + lr];
        #pragma unroll
        for (int e = 0; e < 4; ++e) xm[nt][e] = iv;
    }

    const int sq = w & 3;    // logits s-tile
    const int kh = w >> 2;   // logits K-half

    // A-fragment bases for the wave's 4 nt-quarters (k = w*64 + nt*16 + lr)
    const short* aP0 = A16 + (w * 64 +      lr) * K_DIM + 8 * lg;
    const short* aP1 = A16 + (w * 64 + 16 + lr) * K_DIM + 8 * lg;
    const short* aP2 = A16 + (w * 64 + 32 + lr) * K_DIM + 8 * lg;
    const short* aP3 = A16 + (w * 64 + 48 + lr) * K_DIM + 8 * lg;

    // resident half (nt=0,1): 32 fragments, 128 VGPRs, loaded once
    RESL(0)  RESL(1)  RESL(2)  RESL(3)
    RESL(4)  RESL(5)  RESL(6)  RESL(7)
    RESL(8)  RESL(9)  RESL(10) RESL(11)
    RESL(12) RESL(13) RESL(14) RESL(15)

    float llacc = 0.0f;
    __syncthreads();

    for (int t = 0; t < T_LEN; ++t) {
        // ---- P1: logits partial GEMM (K-half kh): 8 MFMA, all-LDS operands
        f32x4 lga = {0.f, 0.f, 0.f, 0.f};
        #pragma unroll
        for (int i = 0; i < 8; ++i) {
            bf16x8 xa = *(const bf16x8*)(&Xb[lr][kh * 256 + i * 32 + 8 * lg]);
            bf16x8 cb = *(const bf16x8*)(&Cb[sq * 16 + lr][kh * 256 + i * 32 + 8 * lg]);
            MFMA_(xa, cb, lga);
        }
        #pragma unroll
        for (int e = 0; e < 4; ++e)
            Lg[kh][4 * lg + e][sq * 16 + lr] = lga[e];

        // ---- P2: update GEMM. nt=0,1 resident; nt=2,3 depth-4 slice pipeline.
        f32x4 acc0 = {0.f, 0.f, 0.f, 0.f};
        f32x4 acc1 = {0.f, 0.f, 0.f, 0.f};
        f32x4 acc2 = {0.f, 0.f, 0.f, 0.f};
        f32x4 acc3 = {0.f, 0.f, 0.f, 0.f};
        LOADS(0) LOADS(1) LOADS(2) LOADS(3)
        COMPS(0)  LOADS(4)
        COMPS(1)  LOADS(5)
        COMPS(2)  LOADS(6)
        COMPS(3)  LOADS(7)
        COMPS(4)  LOADS(8)
        COMPS(5)  LOADS(9)
        COMPS(6)  LOADS(10)
        COMPS(7)  LOADS(11)
        COMPS(8)  LOADS(12)
        COMPS(9)  LOADS(13)
        COMPS(10) LOADS(14)
        COMPS(11) LOADS(15)
        COMPS(12) COMPS(13) COMPS(14) COMPS(15)
        __syncthreads();   // Xb reads done; Lg writes visible

        // ---- P3: gating in fp32, rewrite Xb (pi/pb gathers consumed in place)
        int mytok[4];
        #pragma unroll
        for (int e = 0; e < 4; ++e) mytok[e] = tokS[4 * lg + e][t];
        #pragma unroll
        for (int nt = 0; nt < 4; ++nt) {
            int k = w * 64 + nt * 16 + lr;
            #pragma unroll
            for (int e = 0; e < 4; ++e) {
                float p  = PI32[mytok[e] * K_DIM + k];
                float pb = PB32[mytok[e] * K_DIM + k];
                float a  = (nt == 0) ? acc0[e] : (nt == 1) ? acc1[e]
                         : (nt == 2) ? acc2[e] : acc3[e];
                float nx = xm[nt][e] + p * (a - xm[nt][e]) + pb;
                xm[nt][e] = nx;
                Xb[4 * lg + e][k] = f2bf(nx);
            }
        }
        // waves 0..3: log-softmax + LL for 4 seqs each (16 lanes/seq, 4 logits/lane)
        if (w < 4) {
            int b = w * 4 + (l >> 4);
            int i = l & 15;
            float v[4];
            #pragma unroll
            for (int c = 0; c < 4; ++c)
                v[c] = Lg[0][b][i * 4 + c] + Lg[1][b][i * 4 + c];
            float m = fmaxf(fmaxf(v[0], v[1]), fmaxf(v[2], v[3]));
            m = fmaxf(m, __shfl_xor(m, 1));
            m = fmaxf(m, __shfl_xor(m, 2));
            m = fmaxf(m, __shfl_xor(m, 4));
            m = fmaxf(m, __shfl_xor(m, 8));
            float sum = expf(v[0] - m) + expf(v[1] - m) + expf(v[2] - m) + expf(v[3] - m);
            sum += __shfl_xor(sum, 1);
            sum += __shfl_xor(sum, 2);
            sum += __shfl_xor(sum, 4);
            sum += __shfl_xor(sum, 8);
            int tok = tokS[b][t];
            float sel = (i == (tok >> 2)) ? v[tok & 3] : 0.0f;
            sel += __shfl_xor(sel, 1);
            sel += __shfl_xor(sel, 2);
            sel += __shfl_xor(sel, 4);
            sel += __shfl_xor(sel, 8);
            llacc += sel - m - logf(sum);
        }
        __syncthreads();   // new Xb visible; Lg consumed
    }

    if (w < 4 && (l & 15) == 0)
        out[b0 + w * 4 + (l >> 4)] = llacc;
}

extern "C" void kernel_launch(void* const* d_in, const int* in_sizes, int n_in,
                              void* d_out, int out_size, void* d_ws, size_t ws_size,
                              hipStream_t stream) {
    const float* A  = (const float*)d_in[0];   // (512,512)
    const float* B  = (const float*)d_in[1];   // (512,64)
    const float* C  = (const float*)d_in[2];   // (64,512)
    const float* Pp = (const float*)d_in[3];   // (64,512)
    const float* init = (const float*)d_in[4]; // (512,)
    const int* tokens = (const int*)d_in[5];   // (512,64)
    float* out = (float*)d_out;

    // workspace layout (needs 851,968 bytes)
    short* A16    = (short*)d_ws;                              // 512*512*2 = 524288
    short* Ceff16 = (short*)((char*)d_ws + 524288);            // 64*512*2  =  65536
    float* PI32   = (float*)((char*)d_ws + 589824);            // 64*512*4  = 131072
    float* PB32   = (float*)((char*)d_ws + 720896);            // 64*512*4  = 131072

    ssm_prep<<<256, 256, 0, stream>>>(A, B, C, Pp, A16, Ceff16, PI32, PB32);
    ssm_main<<<NWG, 512, 0, stream>>>(A16, Ceff16, PI32, PB32, init, tokens, out);
}